// Round 14
// baseline (123.453 us; speedup 1.0000x reference)
//
#include <hip/hip_runtime.h>

typedef __bf16 bf16x8 __attribute__((ext_vector_type(8)));
typedef float f32x4 __attribute__((ext_vector_type(4)));

static __device__ __forceinline__ unsigned short f2bf(float f) {
    union { float f; unsigned int u; } v; v.f = f;
    unsigned int r = v.u + 0x7fffu + ((v.u >> 16) & 1u);
    return (unsigned short)(r >> 16);
}
static __device__ __forceinline__ float blo(unsigned int u) {
    union { unsigned int u; float f; } v; v.u = u << 16; return v.f;
}
static __device__ __forceinline__ float bhi(unsigned int u) {
    union { unsigned int u; float f; } v; v.u = u & 0xffff0000u; return v.f;
}

// ---- fast zero ----
__global__ void zero_kernel(int* __restrict__ p, int n) {
    int i = blockIdx.x * blockDim.x + threadIdx.x;
    int n4 = n >> 2;
    if (i < n4) reinterpret_cast<int4*>(p)[i] = make_int4(0, 0, 0, 0);
    if (i < (n & 3)) p[(n4 << 2) + i] = 0;
}

// ---- fused prep: [0,nh) hist (deg_rd by (r,dst) + per-dst rank eoff) |
//                  [nh,nh+nx) x->bf16 | rest: Wt2[(sl*256+o)][d] transpose ----
__global__ __launch_bounds__(256) void prep_kernel(
    const int* __restrict__ dst, const int* __restrict__ et,
    int* __restrict__ deg_rd, int* __restrict__ cnt_d, int* __restrict__ eoff,
    const float* __restrict__ x, unsigned short* __restrict__ xbf,
    const float* __restrict__ Wr, const float* __restrict__ W0w,
    unsigned short* __restrict__ Wt2,
    int E, int N, int R, int nh, int nx)
{
    __shared__ float t[64][65];
    const int bid = blockIdx.x, tid = threadIdx.x;
    if (bid < nh) {
        int i = bid * 256 + tid;
        if (i < E) {
            int d = dst[i];
            atomicAdd(&deg_rd[et[i] * N + d], 1);
            eoff[i] = atomicAdd(&cnt_d[d], 1);
        }
    } else if (bid < nh + nx) {
        int id = (bid - nh) * 256 + tid;
        int n = id >> 6, c4 = id & 63;
        if (n < N) {
            float4 v = *reinterpret_cast<const float4*>(&x[((size_t)n << 8) + (c4 << 2)]);
            ushort4 h;
            h.x = f2bf(v.x); h.y = f2bf(v.y); h.z = f2bf(v.z); h.w = f2bf(v.w);
            *reinterpret_cast<ushort4*>(&xbf[((size_t)n << 8) + (c4 << 2)]) = h;
        }
    } else {
        int tb = bid - nh - nx;              // (R+1)*16 tiles
        int sl = tb >> 4, d0 = ((tb >> 2) & 3) * 64, o0 = (tb & 3) * 64;
        if (sl < R) {
            #pragma unroll
            for (int j = 0; j < 16; ++j) {
                int idx = j * 256 + tid;
                int dr = idx >> 6, oc = idx & 63;
                t[dr][oc] = Wr[((size_t)sl * 256 + d0 + dr) * 256 + o0 + oc];
            }
            __syncthreads();
            #pragma unroll
            for (int j = 0; j < 4; ++j) {
                int idx = j * 256 + tid;
                int orow = idx >> 4, dc4 = (idx & 15) << 2;
                ushort4 h;
                h.x = f2bf(t[dc4 + 0][orow]); h.y = f2bf(t[dc4 + 1][orow]);
                h.z = f2bf(t[dc4 + 2][orow]); h.w = f2bf(t[dc4 + 3][orow]);
                *reinterpret_cast<ushort4*>(&Wt2[((size_t)sl * 256 + o0 + orow) * 256 + d0 + dc4]) = h;
            }
        } else {
            #pragma unroll
            for (int j = 0; j < 4; ++j) {
                int idx = j * 256 + tid;
                int orow = idx >> 4, dc4 = (idx & 15) << 2;
                float4 v = *reinterpret_cast<const float4*>(&W0w[(size_t)(o0 + orow) * 256 + d0 + dc4]);
                ushort4 h;
                h.x = f2bf(v.x); h.y = f2bf(v.y); h.z = f2bf(v.z); h.w = f2bf(v.w);
                *reinterpret_cast<ushort4*>(&Wt2[((size_t)R * 256 + o0 + orow) * 256 + d0 + dc4]) = h;
            }
        }
    }
}

// ---- 2-level exclusive scan over n bins (chunk=256) ----
__global__ void scan1_kernel(const int* __restrict__ cnt, int* __restrict__ local,
                             int* __restrict__ bsum, int B) {
    __shared__ int tmp[256];
    int t = threadIdx.x, g = blockIdx.x * 256 + t;
    int v = (g < B) ? cnt[g] : 0;
    tmp[t] = v; __syncthreads();
    for (int o = 1; o < 256; o <<= 1) {
        int u = (t >= o) ? tmp[t - o] : 0;
        __syncthreads();
        tmp[t] += u;
        __syncthreads();
    }
    if (g < B) local[g] = tmp[t] - v;
    if (t == 255) bsum[blockIdx.x] = tmp[t];
}

__global__ void scan2_kernel(const int* __restrict__ bsum, int* __restrict__ base, int nc) {
    __shared__ int tmp[1024];
    int t = threadIdx.x;
    int v = (t < nc) ? bsum[t] : 0;
    tmp[t] = v; __syncthreads();
    for (int o = 1; o < 1024; o <<= 1) {
        int u = (t >= o) ? tmp[t - o] : 0;
        __syncthreads();
        tmp[t] += u;
        __syncthreads();
    }
    if (t < nc) base[t] = tmp[t] - v;
}

// ---- bucket edges by dst (atomic-free): srcs2[pos] = {src | r<<20, 1/deg} ----
__global__ void scatter2_kernel(const int* __restrict__ src, const int* __restrict__ dst,
                                const int* __restrict__ et, const int* __restrict__ local,
                                const int* __restrict__ base, const int* __restrict__ eoff,
                                const int* __restrict__ deg_rd, uint2* __restrict__ srcs2,
                                int E, int N) {
    int i = blockIdx.x * blockDim.x + threadIdx.x;
    if (i < E) {
        int d = dst[i], r = et[i];
        int pos = local[d] + base[d >> 8] + eoff[i];
        float sc = 1.0f / (float)deg_rd[r * N + d];
        srcs2[pos] = make_uint2((unsigned)src[i] | ((unsigned)r << 20), __float_as_uint(sc));
    }
}

// ---- dense GEMM: h[M,4352](bf16) = xbf[M,256] * Wt2[4352,256]^T ----
// tile 128x128, 4 waves 2x2; K=256 -> ksteps=4 (BK=64); A dbuf, B single-buffered;
// global_load_lds + XOR swizzle + counted vmcnt(4); LDS-repack epilogue for
// coalesced bf16 writes. Grid (34, ceil(M/128)) = 2686 blocks.
__global__ __launch_bounds__(256) void gemm_h_kernel(
    const unsigned short* __restrict__ S, const unsigned short* __restrict__ Wt2,
    unsigned short* __restrict__ h, int M)
{
    __shared__ __align__(16) unsigned short ldsA[2][8192];
    __shared__ __align__(16) unsigned short ldsB[8192];
    const int tid = threadIdx.x;
    const int lane = tid & 63, w = tid >> 6;
    const int wm = w & 1, wn = w >> 1;
    const int n0 = blockIdx.x * 128, m0 = blockIdx.y * 128;
    const int ksteps = 4;

    f32x4 acc[4][4] = {};

    const int flat_base = w * 4 * 64 + lane;

#define STAGE_A(buf, kstep)                                                               \
    {                                                                                     \
        const int kb = (kstep) * 128;                                                     \
        _Pragma("unroll")                                                                 \
        for (int i = 0; i < 4; ++i) {                                                     \
            int flat = flat_base + i * 64;                                                \
            int row = flat >> 3, seg = flat & 7;                                          \
            int gr = m0 + row; gr = gr < M ? gr : M - 1;                                  \
            const char* gp = (const char*)S + (size_t)gr * 512 + kb                       \
                             + ((seg * 16) ^ ((row & 7) << 4));                           \
            unsigned short* lp = &ldsA[buf][(w * 4 + i) * 512];                           \
            __builtin_amdgcn_global_load_lds(                                             \
                (const __attribute__((address_space(1))) void*)gp,                        \
                (__attribute__((address_space(3))) void*)lp, 16, 0, 0);                   \
        }                                                                                 \
    }

#define STAGE_B(kstep)                                                                    \
    {                                                                                     \
        const int kb = (kstep) * 128;                                                     \
        _Pragma("unroll")                                                                 \
        for (int i = 0; i < 4; ++i) {                                                     \
            int flat = flat_base + i * 64;                                                \
            int row = flat >> 3, seg = flat & 7;                                          \
            const char* gp = (const char*)Wt2 + (size_t)(n0 + row) * 512 + kb             \
                             + ((seg * 16) ^ ((row & 7) << 4));                           \
            unsigned short* lp = &ldsB[(w * 4 + i) * 512];                                \
            __builtin_amdgcn_global_load_lds(                                             \
                (const __attribute__((address_space(1))) void*)gp,                        \
                (__attribute__((address_space(3))) void*)lp, 16, 0, 0);                   \
        }                                                                                 \
    }

#define COMPUTE(buf)                                                                      \
    {                                                                                     \
        _Pragma("unroll")                                                                 \
        for (int kk = 0; kk < 2; ++kk) {                                                  \
            bf16x8 af[4], bfr[4];                                                         \
            _Pragma("unroll")                                                             \
            for (int m = 0; m < 4; ++m) {                                                 \
                int row = wm * 64 + m * 16 + (lane & 15);                                 \
                int colb = (kk * 64 + ((lane >> 4) << 4)) ^ ((row & 7) << 4);             \
                af[m] = *reinterpret_cast<const bf16x8*>(                                 \
                    (const char*)&ldsA[buf][0] + row * 128 + colb);                       \
            }                                                                             \
            _Pragma("unroll")                                                             \
            for (int n = 0; n < 4; ++n) {                                                 \
                int row = wn * 64 + n * 16 + (lane & 15);                                 \
                int colb = (kk * 64 + ((lane >> 4) << 4)) ^ ((row & 7) << 4);             \
                bfr[n] = *reinterpret_cast<const bf16x8*>(                                \
                    (const char*)&ldsB[0] + row * 128 + colb);                            \
            }                                                                             \
            __builtin_amdgcn_s_setprio(1);                                                \
            _Pragma("unroll")                                                             \
            for (int m = 0; m < 4; ++m)                                                   \
                _Pragma("unroll")                                                         \
                for (int n = 0; n < 4; ++n)                                               \
                    acc[m][n] = __builtin_amdgcn_mfma_f32_16x16x32_bf16(                  \
                        af[m], bfr[n], acc[m][n], 0, 0, 0);                               \
            __builtin_amdgcn_s_setprio(0);                                                \
        }                                                                                 \
    }

    STAGE_A(0, 0)
    STAGE_B(0)
    STAGE_A(1, 1)
    asm volatile("s_waitcnt vmcnt(4)" ::: "memory");
    __builtin_amdgcn_s_barrier();

    for (int t = 0; t < ksteps; ++t) {
        COMPUTE(t & 1)
        asm volatile("s_waitcnt lgkmcnt(0)" ::: "memory");
        __builtin_amdgcn_sched_barrier(0);
        __builtin_amdgcn_s_barrier();
        if (t + 1 < ksteps) {
            STAGE_B(t + 1)
            if (t + 2 < ksteps) {
                STAGE_A(t & 1, t + 2)
                asm volatile("s_waitcnt vmcnt(4)" ::: "memory");
            } else {
                asm volatile("s_waitcnt vmcnt(0)" ::: "memory");
            }
            __builtin_amdgcn_s_barrier();
        }
    }
#undef STAGE_A
#undef STAGE_B
#undef COMPUTE

    // ---- epilogue: repack acc -> LDS bf16 tile, then coalesced 16B stores ----
    unsigned short* ldsC = &ldsA[0][0];   // 32 KB, free after final barrier
    const int lr = wm * 64 + ((lane >> 4) << 2);
    const int lc = wn * 64 + (lane & 15);
    #pragma unroll
    for (int n = 0; n < 4; ++n)
        #pragma unroll
        for (int m = 0; m < 4; ++m)
            #pragma unroll
            for (int j = 0; j < 4; ++j)
                ldsC[(lr + m * 16 + j) * 128 + lc + n * 16] = f2bf(acc[m][n][j]);
    __syncthreads();
    #pragma unroll
    for (int i = 0; i < 8; ++i) {
        int idx = tid + i * 256;          // 0..2047
        int row = idx >> 4, ch = idx & 15;
        int gr = m0 + row;
        if (gr < M)
            *reinterpret_cast<uint4*>(&h[(size_t)gr * 4352 + n0 + ch * 8]) =
                *reinterpret_cast<const uint4*>(&ldsC[row * 128 + ch * 8]);
    }
}

// ---- gather-reduce to out: half-wave per dst node ----
// out[dn][:] = sum_e scale_e * h[src_e][r_e*256:+256] + h[dn][4096:+256] + bias
__global__ __launch_bounds__(256) void reduce2_kernel(
    const uint2* __restrict__ srcs2, const int* __restrict__ cnt_d,
    const int* __restrict__ local, const int* __restrict__ base,
    const unsigned short* __restrict__ h, const float* __restrict__ bias,
    float* __restrict__ out, int N)
{
    const int dn = blockIdx.x * 8 + (threadIdx.x >> 5);
    if (dn >= N) return;
    const int lane = threadIdx.x & 31;
    const int cnt = cnt_d[dn];
    const int st  = local[dn] + base[dn >> 8];

    float a0 = 0.f, a1 = 0.f, a2 = 0.f, a3 = 0.f;
    float a4 = 0.f, a5 = 0.f, a6 = 0.f, a7 = 0.f;
    for (int c0 = 0; c0 < cnt; c0 += 32) {
        uint2 pv = make_uint2(0u, 0u);
        if (c0 + lane < cnt) pv = srcs2[st + c0 + lane];
        int m = cnt - c0; if (m > 32) m = 32;
        for (int i = 0; i < m; ++i) {
            unsigned w0 = (unsigned)__shfl((int)pv.x, i, 32);
            float sc = __int_as_float(__shfl((int)pv.y, i, 32));
            int sn = (int)(w0 & 0xFFFFFu), r = (int)(w0 >> 20);
            const uint4 v = *reinterpret_cast<const uint4*>(
                &h[(size_t)sn * 4352 + r * 256 + (lane << 3)]);
            a0 += sc * blo(v.x); a1 += sc * bhi(v.x);
            a2 += sc * blo(v.y); a3 += sc * bhi(v.y);
            a4 += sc * blo(v.z); a5 += sc * bhi(v.z);
            a6 += sc * blo(v.w); a7 += sc * bhi(v.w);
        }
    }
    // self-loop slice + bias
    const uint4 sv = *reinterpret_cast<const uint4*>(&h[(size_t)dn * 4352 + 4096 + (lane << 3)]);
    const float4 b0 = *reinterpret_cast<const float4*>(&bias[(lane << 3)]);
    const float4 b1 = *reinterpret_cast<const float4*>(&bias[(lane << 3) + 4]);
    float4 o0, o1;
    o0.x = a0 + blo(sv.x) + b0.x; o0.y = a1 + bhi(sv.x) + b0.y;
    o0.z = a2 + blo(sv.y) + b0.z; o0.w = a3 + bhi(sv.y) + b0.w;
    o1.x = a4 + blo(sv.z) + b1.x; o1.y = a5 + bhi(sv.z) + b1.y;
    o1.z = a6 + blo(sv.w) + b1.z; o1.w = a7 + bhi(sv.w) + b1.w;
    *reinterpret_cast<float4*>(&out[(size_t)dn * 256 + (lane << 3)]) = o0;
    *reinterpret_cast<float4*>(&out[(size_t)dn * 256 + (lane << 3) + 4]) = o1;
}

extern "C" void kernel_launch(void* const* d_in, const int* in_sizes, int n_in,
                              void* d_out, int out_size, void* d_ws, size_t ws_size,
                              hipStream_t stream) {
    const float* x   = (const float*)d_in[0];
    const float* Wr  = (const float*)d_in[1];
    const float* W0w = (const float*)d_in[2];
    const float* W0b = (const float*)d_in[3];
    const int*   eidx= (const int*)d_in[4];
    const int*   et  = (const int*)d_in[5];
    const int N = in_sizes[0] / 256;      // nodes (10000)
    const int R = in_sizes[1] / 65536;    // relations (16)
    const int E = in_sizes[5];            // edges (320000)
    const int* src = eidx;
    const int* dst = eidx + E;
    float* out = (float*)d_out;

    const int B = R * N;                  // (r,dst) bins for deg
    const int NC2 = (N + 255) / 256;      // dst-scan chunks (40)
    const int K = (R + 1) * 256;          // 4352

    // ---- workspace: deg_rd | cnt_d | local | bsum | base | eoff | srcs2 | xbf | Wt2 | h ----
    char* ws = (char*)d_ws;
    size_t off = 0;
    auto alloc = [&](size_t bytes) { void* p = ws + off; off = (off + bytes + 255) & ~(size_t)255; return p; };
    int* deg_rd = (int*)alloc((size_t)B * 4);
    int* cnt_d  = (int*)alloc((size_t)N * 4);
    int* local  = (int*)alloc((size_t)N * 4);
    int* bsum   = (int*)alloc(4096);
    int* base   = (int*)alloc(4096);
    int* eoff   = (int*)alloc((size_t)E * 4);
    uint2* srcs2 = (uint2*)alloc((size_t)E * 8);
    unsigned short* xbf = (unsigned short*)alloc((size_t)N * 256 * 2);
    unsigned short* Wt2 = (unsigned short*)alloc((size_t)K * 256 * 2);
    unsigned short* h   = (unsigned short*)alloc((size_t)N * K * 2);
    (void)ws_size;

    // zero deg_rd + cnt_d (contiguous)
    zero_kernel<<<((B + N) / 4 + 255) / 256, 256, 0, stream>>>(deg_rd, B + N);
    {
        const int nh = (E + 255) / 256;
        const int nx = (N * 64 + 255) / 256;
        const int nwT = (R + 1) * 16;
        prep_kernel<<<nh + nx + nwT, 256, 0, stream>>>(dst, et, deg_rd, cnt_d, eoff,
                                                       x, xbf, Wr, W0w, Wt2, E, N, R, nh, nx);
    }
    scan1_kernel<<<NC2, 256, 0, stream>>>(cnt_d, local, bsum, N);
    scan2_kernel<<<1, 1024, 0, stream>>>(bsum, base, NC2);
    scatter2_kernel<<<(E + 255) / 256, 256, 0, stream>>>(src, dst, et, local, base, eoff,
                                                         deg_rd, srcs2, E, N);
    {
        dim3 grid(K / 128, (N + 127) / 128);   // (34, 79)
        gemm_h_kernel<<<grid, 256, 0, stream>>>(xbf, Wt2, h, N);
    }
    reduce2_kernel<<<(N + 7) / 8, 256, 0, stream>>>(srcs2, cnt_d, local, base, h, W0b, out, N);
}